// Round 12
// baseline (132.392 us; speedup 1.0000x reference)
//
#include <hip/hip_runtime.h>

#define HH 160
#define WW 160
#define DD 16
#define NG 8192
#define VOXEL 0.4f

// binning tiles: 20 x 20 x 4 (each 8x8x4 voxels) = 1600 tiles
// voxelize blocks: ONE WAVE each, 4 per tile (one per 4x4 i,j-quadrant)
#define TTX 20
#define TTY 20
#define TTZ 4
#define NTILES (TTX * TTY * TTZ)
#define CAP 128   // survivors per tile: lambda ~61, P(>128) ~ 8.6 sigma -> safe

// d_ws layout:
//   tileCnt  : NTILES int (6.4 KB)                @ 0
//   tilePack : NTILES * CAP * 4 float4 (13.1 MB)  @ 64 KB
// tilePack record (4 float4 = 64 B, list-order inline; feats stay in the
// small L2-hot input buffer, fetched by embedded index):
//   [0] = (mu.x, mu.y, mu.z, opacity)
//   [1] = (3sx,  3sy,  3sz,  ci00)
//   [2] = (ci01, ci02, ci11, ci12)
//   [3] = (ci22, as_float(g), 0, 0)

__global__ __launch_bounds__(64) void gv_precompute_bin(
    const float* __restrict__ means, const float* __restrict__ opac,
    const float* __restrict__ scales, const float* __restrict__ rots,
    int* __restrict__ tileCnt, float4* __restrict__ tilePack) {
  int g = blockIdx.x * 64 + threadIdx.x;
  if (g >= NG) return;
  float qw = rots[g * 4 + 0], qx = rots[g * 4 + 1];
  float qy = rots[g * 4 + 2], qz = rots[g * 4 + 3];
  float inv = rsqrtf(qw * qw + qx * qx + qy * qy + qz * qz);
  qw *= inv; qx *= inv; qy *= inv; qz *= inv;
  float R[3][3];
  R[0][0] = 1.f - 2.f * (qy * qy + qz * qz);
  R[0][1] = 2.f * (qx * qy - qw * qz);
  R[0][2] = 2.f * (qx * qz + qw * qy);
  R[1][0] = 2.f * (qx * qy + qw * qz);
  R[1][1] = 1.f - 2.f * (qx * qx + qz * qz);
  R[1][2] = 2.f * (qy * qz - qw * qx);
  R[2][0] = 2.f * (qx * qz - qw * qy);
  R[2][1] = 2.f * (qy * qz + qw * qx);
  R[2][2] = 1.f - 2.f * (qx * qx + qy * qy);
  float sx = scales[g * 3 + 0], sy = scales[g * 3 + 1], sz = scales[g * 3 + 2];
  float s2[3] = {sx * sx, sy * sy, sz * sz};
  float is2[3] = {1.f / s2[0], 1.f / s2[1], 1.f / s2[2]};
  float cov00 = 0.f, cov11 = 0.f, cov22 = 0.f;
  float ci00 = 0.f, ci01 = 0.f, ci02 = 0.f, ci11 = 0.f, ci12 = 0.f, ci22 = 0.f;
#pragma unroll
  for (int c = 0; c < 3; c++) {
    cov00 += R[0][c] * R[0][c] * s2[c];
    cov11 += R[1][c] * R[1][c] * s2[c];
    cov22 += R[2][c] * R[2][c] * s2[c];
    ci00 += R[0][c] * R[0][c] * is2[c];
    ci01 += R[0][c] * R[1][c] * is2[c];
    ci02 += R[0][c] * R[2][c] * is2[c];
    ci11 += R[1][c] * R[1][c] * is2[c];
    ci12 += R[1][c] * R[2][c] * is2[c];
    ci22 += R[2][c] * R[2][c] * is2[c];
  }
  float mx = means[g * 3 + 0], my = means[g * 3 + 1], mz = means[g * 3 + 2];
  float bx = 3.f * sqrtf(cov00), by = 3.f * sqrtf(cov11), bz = 3.f * sqrtf(cov22);

  // voxel-center index ranges covered by bbox (with float-slop margin)
  const float eps = 1e-4f;
  int i0 = (int)ceilf((mx - bx + 32.f) * 2.5f - 0.5f - eps);
  int i1 = (int)floorf((mx + bx + 32.f) * 2.5f - 0.5f + eps);
  int j0 = (int)ceilf((my - by + 32.f) * 2.5f - 0.5f - eps);
  int j1 = (int)floorf((my + by + 32.f) * 2.5f - 0.5f + eps);
  int k0 = (int)ceilf((mz - bz + 1.f) * 2.5f - 0.5f - eps);
  int k1 = (int)floorf((mz + bz + 1.f) * 2.5f - 0.5f + eps);
  i0 = max(i0, 0); i1 = min(i1, HH - 1);
  j0 = max(j0, 0); j1 = min(j1, WW - 1);
  k0 = max(k0, 0); k1 = min(k1, DD - 1);
  if (i0 > i1 || j0 > j1 || k0 > k1) return;

  float4 p0 = make_float4(mx, my, mz, opac[g]);
  float4 p1 = make_float4(bx, by, bz, ci00);
  float4 p2 = make_float4(ci01, ci02, ci11, ci12);
  float4 p3 = make_float4(ci22, __int_as_float(g), 0.f, 0.f);

  int ti0 = i0 >> 3, ti1 = i1 >> 3;
  int tj0 = j0 >> 3, tj1 = j1 >> 3;
  int tk0 = k0 >> 2, tk1 = k1 >> 2;
  for (int ti = ti0; ti <= ti1; ti++)
    for (int tj = tj0; tj <= tj1; tj++)
      for (int tk = tk0; tk <= tk1; tk++) {
        int t = (ti * TTY + tj) * TTZ + tk;
        int pos = atomicAdd(&tileCnt[t], 1);
        if (pos < CAP) {
          float4* __restrict__ d = tilePack + ((size_t)t * CAP + pos) * 4;
          d[0] = p0;  d[1] = p1;  d[2] = p2;  d[3] = p3;
        }
      }
}

// Voxelize: ONE WAVE per block, 4 blocks per coarse tile (one per 4x4x4
// quadrant). Inner loop identical to the verified R11 loop (LDS pack
// broadcast + L2-hot feats s_load, 2-wide). Geometry change only: 6400
// independent 1-wave blocks -> ~20 blocks/CU resident (vs ~3 of the
// 256-thread version), independent retirement, fine-grained balance.
__global__ __launch_bounds__(64) void gv_voxelize(
    const float4* __restrict__ feats, const int* __restrict__ tileCnt,
    const float4* __restrict__ tilePack, float4* __restrict__ out) {
  __shared__ float4 s_pack[CAP * 4];   // 8 KB

  int l = threadIdx.x;
  int bz = blockIdx.z;
  int ti = bz >> 2, q = bz & 3;        // coarse tile i, quadrant
  int tj = blockIdx.y, tk = blockIdx.x;
  int qi = q >> 1, qj = q & 1;
  int di = qi * 4 + (l >> 4);
  int dj = qj * 4 + ((l >> 2) & 3);
  int dk = l & 3;
  int i = ti * 8 + di, j = tj * 8 + dj, k = tk * 4 + dk;

  float px = (i + 0.5f) * VOXEL - 32.f;
  float py = (j + 0.5f) * VOXEL - 32.f;
  float pz = (k + 0.5f) * VOXEL - 1.f;

  int t = (ti * TTY + tj) * TTZ + tk;
  int cnt = tileCnt[t];
  cnt = min(cnt, CAP);

  // stage pack records (coalesced, parallel; 64 lanes)
  {
    const float4* __restrict__ src = tilePack + (size_t)t * CAP * 4;
    int tot = cnt * 4;
    for (int m = l; m < tot; m += 64) s_pack[m] = src[m];
  }
  __syncthreads();

  float4 acc[8];
#pragma unroll
  for (int f = 0; f < 8; f++) acc[f] = make_float4(0.f, 0.f, 0.f, 0.f);

  int n = 0;
  for (; n + 2 <= cnt; n += 2) {
    float4 a0 = s_pack[n * 4 + 0], b0 = s_pack[n * 4 + 1];
    float4 c0 = s_pack[n * 4 + 2], d0 = s_pack[n * 4 + 3];
    float4 a1 = s_pack[n * 4 + 4], b1 = s_pack[n * 4 + 5];
    float4 c1 = s_pack[n * 4 + 6], d1 = s_pack[n * 4 + 7];

    int g0 = __builtin_amdgcn_readfirstlane(__float_as_int(d0.y));
    int g1 = __builtin_amdgcn_readfirstlane(__float_as_int(d1.y));
    const float4* __restrict__ fp0 = feats + (size_t)g0 * 8;
    const float4* __restrict__ fp1 = feats + (size_t)g1 * 8;
    // issue both feats load sets early (uniform -> s_load_dwordx16 pairs)
    float4 F0[8], F1[8];
#pragma unroll
    for (int f = 0; f < 8; f++) F0[f] = fp0[f];
#pragma unroll
    for (int f = 0; f < 8; f++) F1[f] = fp1[f];

    float dx0 = px - a0.x, dy0 = py - a0.y, dz0 = pz - a0.z;
    float dx1 = px - a1.x, dy1 = py - a1.y, dz1 = pz - a1.z;
    bool in0 = (fabsf(dx0) <= b0.x) & (fabsf(dy0) <= b0.y) & (fabsf(dz0) <= b0.z);
    bool in1 = (fabsf(dx1) <= b1.x) & (fabsf(dy1) <= b1.y) & (fabsf(dz1) <= b1.z);

    if (__any(in0)) {
      float maha = b0.w * dx0 * dx0 + c0.z * dy0 * dy0 + d0.x * dz0 * dz0 +
                   2.f * (c0.x * dx0 * dy0 + c0.y * dx0 * dz0 + c0.w * dy0 * dz0);
      float wgt = in0 ? a0.w * __expf(-0.5f * maha) : 0.f;
#pragma unroll
      for (int f = 0; f < 8; f++) {
        acc[f].x += wgt * F0[f].x;
        acc[f].y += wgt * F0[f].y;
        acc[f].z += wgt * F0[f].z;
        acc[f].w += wgt * F0[f].w;
      }
    }
    if (__any(in1)) {
      float maha = b1.w * dx1 * dx1 + c1.z * dy1 * dy1 + d1.x * dz1 * dz1 +
                   2.f * (c1.x * dx1 * dy1 + c1.y * dx1 * dz1 + c1.w * dy1 * dz1);
      float wgt = in1 ? a1.w * __expf(-0.5f * maha) : 0.f;
#pragma unroll
      for (int f = 0; f < 8; f++) {
        acc[f].x += wgt * F1[f].x;
        acc[f].y += wgt * F1[f].y;
        acc[f].z += wgt * F1[f].z;
        acc[f].w += wgt * F1[f].w;
      }
    }
  }
  if (n < cnt) {
    float4 pa = s_pack[n * 4 + 0], pb = s_pack[n * 4 + 1];
    float4 pc = s_pack[n * 4 + 2], pd = s_pack[n * 4 + 3];
    int gg = __builtin_amdgcn_readfirstlane(__float_as_int(pd.y));
    const float4* __restrict__ fp = feats + (size_t)gg * 8;
    float dx = px - pa.x, dy = py - pa.y, dz = pz - pa.z;
    bool in = (fabsf(dx) <= pb.x) & (fabsf(dy) <= pb.y) & (fabsf(dz) <= pb.z);
    if (__any(in)) {
      float maha = pb.w * dx * dx + pc.z * dy * dy + pd.x * dz * dz +
                   2.f * (pc.x * dx * dy + pc.y * dx * dz + pc.w * dy * dz);
      float wgt = in ? pa.w * __expf(-0.5f * maha) : 0.f;
#pragma unroll
      for (int f = 0; f < 8; f++) {
        float4 fv = fp[f];
        acc[f].x += wgt * fv.x;
        acc[f].y += wgt * fv.y;
        acc[f].z += wgt * fv.z;
        acc[f].w += wgt * fv.w;
      }
    }
  }

  size_t v = ((size_t)i * WW + j) * DD + k;
  float4* o = out + v * 8;
#pragma unroll
  for (int f = 0; f < 8; f++) o[f] = acc[f];
}

extern "C" void kernel_launch(void* const* d_in, const int* in_sizes, int n_in,
                              void* d_out, int out_size, void* d_ws, size_t ws_size,
                              hipStream_t stream) {
  const float* means  = (const float*)d_in[0];
  const float* opac   = (const float*)d_in[1];
  const float* scales = (const float*)d_in[2];
  const float* rots   = (const float*)d_in[3];
  const float4* feats = (const float4*)d_in[4];

  char* ws = (char*)d_ws;
  int* tileCnt     = (int*)ws;                        // 6.4 KB
  float4* tilePack = (float4*)(ws + 64 * 1024);       // 13.1 MB

  hipMemsetAsync(tileCnt, 0, NTILES * sizeof(int), stream);
  gv_precompute_bin<<<128, 64, 0, stream>>>(means, opac, scales, rots,
                                            tileCnt, tilePack);
  dim3 grid(TTZ, TTY, TTX * 4);   // 4 one-wave blocks per coarse tile
  gv_voxelize<<<grid, 64, 0, stream>>>(feats, tileCnt, tilePack,
                                       (float4*)d_out);
}

// Round 13
// 121.640 us; speedup vs baseline: 1.0884x; 1.0884x over previous
//
#include <hip/hip_runtime.h>

#define HH 160
#define WW 160
#define DD 16
#define NG 8192
#define VOXEL 0.4f

// tiles: 20 x 20 x 4 (each 8x8x4 voxels) = 1600 tiles
#define TTX 20
#define TTY 20
#define TTZ 4
#define NTILES (TTX * TTY * TTZ)
#define CAP 128   // survivors per tile: lambda ~61, P(>128) ~ 8.6 sigma -> safe

// d_ws layout:
//   tileCnt  : NTILES int (6.4 KB)                @ 0
//   tilePack : NTILES * CAP * 4 float4 (13.1 MB)  @ 64 KB
// tilePack record (4 float4 = 64 B). Layout chosen so the voxelize inner
// loop reads only [0],[1] for the bbox gate (+index for early feats issue);
// [2],[3] are read ONLY when the wave passes the gate -> ~30% less LDS
// traffic (the measured bottleneck pipe at R11):
//   [0] = (mu.x, mu.y, mu.z, opacity)
//   [1] = (3sx,  3sy,  3sz,  as_float(g))
//   [2] = (ci00, ci01, ci02, ci11)
//   [3] = (ci12, ci22, 0, 0)

__global__ __launch_bounds__(64) void gv_precompute_bin(
    const float* __restrict__ means, const float* __restrict__ opac,
    const float* __restrict__ scales, const float* __restrict__ rots,
    int* __restrict__ tileCnt, float4* __restrict__ tilePack) {
  int g = blockIdx.x * 64 + threadIdx.x;
  if (g >= NG) return;
  float qw = rots[g * 4 + 0], qx = rots[g * 4 + 1];
  float qy = rots[g * 4 + 2], qz = rots[g * 4 + 3];
  float inv = rsqrtf(qw * qw + qx * qx + qy * qy + qz * qz);
  qw *= inv; qx *= inv; qy *= inv; qz *= inv;
  float R[3][3];
  R[0][0] = 1.f - 2.f * (qy * qy + qz * qz);
  R[0][1] = 2.f * (qx * qy - qw * qz);
  R[0][2] = 2.f * (qx * qz + qw * qy);
  R[1][0] = 2.f * (qx * qy + qw * qz);
  R[1][1] = 1.f - 2.f * (qx * qx + qz * qz);
  R[1][2] = 2.f * (qy * qz - qw * qx);
  R[2][0] = 2.f * (qx * qz - qw * qy);
  R[2][1] = 2.f * (qy * qz + qw * qx);
  R[2][2] = 1.f - 2.f * (qx * qx + qy * qy);
  float sx = scales[g * 3 + 0], sy = scales[g * 3 + 1], sz = scales[g * 3 + 2];
  float s2[3] = {sx * sx, sy * sy, sz * sz};
  float is2[3] = {1.f / s2[0], 1.f / s2[1], 1.f / s2[2]};
  float cov00 = 0.f, cov11 = 0.f, cov22 = 0.f;
  float ci00 = 0.f, ci01 = 0.f, ci02 = 0.f, ci11 = 0.f, ci12 = 0.f, ci22 = 0.f;
#pragma unroll
  for (int c = 0; c < 3; c++) {
    cov00 += R[0][c] * R[0][c] * s2[c];
    cov11 += R[1][c] * R[1][c] * s2[c];
    cov22 += R[2][c] * R[2][c] * s2[c];
    ci00 += R[0][c] * R[0][c] * is2[c];
    ci01 += R[0][c] * R[1][c] * is2[c];
    ci02 += R[0][c] * R[2][c] * is2[c];
    ci11 += R[1][c] * R[1][c] * is2[c];
    ci12 += R[1][c] * R[2][c] * is2[c];
    ci22 += R[2][c] * R[2][c] * is2[c];
  }
  float mx = means[g * 3 + 0], my = means[g * 3 + 1], mz = means[g * 3 + 2];
  float bx = 3.f * sqrtf(cov00), by = 3.f * sqrtf(cov11), bz = 3.f * sqrtf(cov22);

  // voxel-center index ranges covered by bbox (with float-slop margin)
  const float eps = 1e-4f;
  int i0 = (int)ceilf((mx - bx + 32.f) * 2.5f - 0.5f - eps);
  int i1 = (int)floorf((mx + bx + 32.f) * 2.5f - 0.5f + eps);
  int j0 = (int)ceilf((my - by + 32.f) * 2.5f - 0.5f - eps);
  int j1 = (int)floorf((my + by + 32.f) * 2.5f - 0.5f + eps);
  int k0 = (int)ceilf((mz - bz + 1.f) * 2.5f - 0.5f - eps);
  int k1 = (int)floorf((mz + bz + 1.f) * 2.5f - 0.5f + eps);
  i0 = max(i0, 0); i1 = min(i1, HH - 1);
  j0 = max(j0, 0); j1 = min(j1, WW - 1);
  k0 = max(k0, 0); k1 = min(k1, DD - 1);
  if (i0 > i1 || j0 > j1 || k0 > k1) return;

  float4 p0 = make_float4(mx, my, mz, opac[g]);
  float4 p1 = make_float4(bx, by, bz, __int_as_float(g));
  float4 p2 = make_float4(ci00, ci01, ci02, ci11);
  float4 p3 = make_float4(ci12, ci22, 0.f, 0.f);

  int ti0 = i0 >> 3, ti1 = i1 >> 3;
  int tj0 = j0 >> 3, tj1 = j1 >> 3;
  int tk0 = k0 >> 2, tk1 = k1 >> 2;
  for (int ti = ti0; ti <= ti1; ti++)
    for (int tj = tj0; tj <= tj1; tj++)
      for (int tk = tk0; tk <= tk1; tk++) {
        int t = (ti * TTY + tj) * TTZ + tk;
        int pos = atomicAdd(&tileCnt[t], 1);
        if (pos < CAP) {
          float4* __restrict__ d = tilePack + ((size_t)t * CAP + pos) * 4;
          d[0] = p0;  d[1] = p1;  d[2] = p2;  d[3] = p3;
        }
      }
}

// Voxelize: R11 structure (LDS pack broadcast + L2-hot feats s_load,
// 2-wide, 4 waves/block) with gated ci reads: LDS was the saturated pipe
// (4 ds_read_b128/gaussian ~= 30us ~= measured 33us; VALUBusy only 16%).
// Reads [2],[3] now execute only when __any(in) -> expected LDS traffic
// x0.6-0.75. Feats s_loads stay early/unconditional (index rides in [1].w).
__global__ __launch_bounds__(256) void gv_voxelize(
    const float4* __restrict__ feats, const int* __restrict__ tileCnt,
    const float4* __restrict__ tilePack, float4* __restrict__ out) {
  __shared__ float4 s_pack[CAP * 4];   // 8 KB

  int tid = threadIdx.x;
  int dk = tid & 3, dj = (tid >> 2) & 7, di = tid >> 5;
  int tk = blockIdx.x, tj = blockIdx.y, ti = blockIdx.z;
  int i = ti * 8 + di, j = tj * 8 + dj, k = tk * 4 + dk;

  float px = (i + 0.5f) * VOXEL - 32.f;
  float py = (j + 0.5f) * VOXEL - 32.f;
  float pz = (k + 0.5f) * VOXEL - 1.f;

  int t = (ti * TTY + tj) * TTZ + tk;
  int cnt = tileCnt[t];
  cnt = min(cnt, CAP);

  // stage pack records (coalesced, parallel)
  {
    const float4* __restrict__ src = tilePack + (size_t)t * CAP * 4;
    int tot = cnt * 4;
    for (int m = tid; m < tot; m += 256) s_pack[m] = src[m];
  }
  __syncthreads();

  float4 acc[8];
#pragma unroll
  for (int f = 0; f < 8; f++) acc[f] = make_float4(0.f, 0.f, 0.f, 0.f);

  int n = 0;
  for (; n + 2 <= cnt; n += 2) {
    float4 a0 = s_pack[n * 4 + 0], b0 = s_pack[n * 4 + 1];
    float4 a1 = s_pack[n * 4 + 4], b1 = s_pack[n * 4 + 5];

    int g0 = __builtin_amdgcn_readfirstlane(__float_as_int(b0.w));
    int g1 = __builtin_amdgcn_readfirstlane(__float_as_int(b1.w));
    const float4* __restrict__ fp0 = feats + (size_t)g0 * 8;
    const float4* __restrict__ fp1 = feats + (size_t)g1 * 8;
    // issue both feats load sets early (uniform -> s_load_dwordx16 pairs)
    float4 F0[8], F1[8];
#pragma unroll
    for (int f = 0; f < 8; f++) F0[f] = fp0[f];
#pragma unroll
    for (int f = 0; f < 8; f++) F1[f] = fp1[f];

    float dx0 = px - a0.x, dy0 = py - a0.y, dz0 = pz - a0.z;
    float dx1 = px - a1.x, dy1 = py - a1.y, dz1 = pz - a1.z;
    bool in0 = (fabsf(dx0) <= b0.x) & (fabsf(dy0) <= b0.y) & (fabsf(dz0) <= b0.z);
    bool in1 = (fabsf(dx1) <= b1.x) & (fabsf(dy1) <= b1.y) & (fabsf(dz1) <= b1.z);

    if (__any(in0)) {
      float4 c0 = s_pack[n * 4 + 2], d0 = s_pack[n * 4 + 3];
      float maha = c0.x * dx0 * dx0 + c0.w * dy0 * dy0 + d0.y * dz0 * dz0 +
                   2.f * (c0.y * dx0 * dy0 + c0.z * dx0 * dz0 + d0.x * dy0 * dz0);
      float wgt = in0 ? a0.w * __expf(-0.5f * maha) : 0.f;
#pragma unroll
      for (int f = 0; f < 8; f++) {
        acc[f].x += wgt * F0[f].x;
        acc[f].y += wgt * F0[f].y;
        acc[f].z += wgt * F0[f].z;
        acc[f].w += wgt * F0[f].w;
      }
    }
    if (__any(in1)) {
      float4 c1 = s_pack[n * 4 + 6], d1 = s_pack[n * 4 + 7];
      float maha = c1.x * dx1 * dx1 + c1.w * dy1 * dy1 + d1.y * dz1 * dz1 +
                   2.f * (c1.y * dx1 * dy1 + c1.z * dx1 * dz1 + d1.x * dy1 * dz1);
      float wgt = in1 ? a1.w * __expf(-0.5f * maha) : 0.f;
#pragma unroll
      for (int f = 0; f < 8; f++) {
        acc[f].x += wgt * F1[f].x;
        acc[f].y += wgt * F1[f].y;
        acc[f].z += wgt * F1[f].z;
        acc[f].w += wgt * F1[f].w;
      }
    }
  }
  if (n < cnt) {
    float4 pa = s_pack[n * 4 + 0], pb = s_pack[n * 4 + 1];
    int gg = __builtin_amdgcn_readfirstlane(__float_as_int(pb.w));
    const float4* __restrict__ fp = feats + (size_t)gg * 8;
    float dx = px - pa.x, dy = py - pa.y, dz = pz - pa.z;
    bool in = (fabsf(dx) <= pb.x) & (fabsf(dy) <= pb.y) & (fabsf(dz) <= pb.z);
    if (__any(in)) {
      float4 pc = s_pack[n * 4 + 2], pd = s_pack[n * 4 + 3];
      float maha = pc.x * dx * dx + pc.w * dy * dy + pd.y * dz * dz +
                   2.f * (pc.y * dx * dy + pc.z * dx * dz + pd.x * dy * dz);
      float wgt = in ? pa.w * __expf(-0.5f * maha) : 0.f;
#pragma unroll
      for (int f = 0; f < 8; f++) {
        float4 fv = fp[f];
        acc[f].x += wgt * fv.x;
        acc[f].y += wgt * fv.y;
        acc[f].z += wgt * fv.z;
        acc[f].w += wgt * fv.w;
      }
    }
  }

  size_t v = ((size_t)i * WW + j) * DD + k;
  float4* o = out + v * 8;
#pragma unroll
  for (int f = 0; f < 8; f++) o[f] = acc[f];
}

extern "C" void kernel_launch(void* const* d_in, const int* in_sizes, int n_in,
                              void* d_out, int out_size, void* d_ws, size_t ws_size,
                              hipStream_t stream) {
  const float* means  = (const float*)d_in[0];
  const float* opac   = (const float*)d_in[1];
  const float* scales = (const float*)d_in[2];
  const float* rots   = (const float*)d_in[3];
  const float4* feats = (const float4*)d_in[4];

  char* ws = (char*)d_ws;
  int* tileCnt     = (int*)ws;                        // 6.4 KB
  float4* tilePack = (float4*)(ws + 64 * 1024);       // 13.1 MB

  hipMemsetAsync(tileCnt, 0, NTILES * sizeof(int), stream);
  gv_precompute_bin<<<128, 64, 0, stream>>>(means, opac, scales, rots,
                                            tileCnt, tilePack);
  dim3 grid(TTZ, TTY, TTX);
  gv_voxelize<<<grid, 256, 0, stream>>>(feats, tileCnt, tilePack,
                                        (float4*)d_out);
}